// Round 14
// baseline (271.833 us; speedup 1.0000x reference)
//
#include <hip/hip_runtime.h>

#define B_N 131072
#define IN_N 40
#define H_N 256

typedef __bf16 bf16x8 __attribute__((ext_vector_type(8)));
typedef float f32x4 __attribute__((ext_vector_type(4)));

#define MFMA(a, b, c) __builtin_amdgcn_mfma_f32_16x16x32_bf16(a, b, c, 0, 0, 0)

// ws bf16 layout (identical to v13/v14 — verified):
//   quarter q (64 hcols): gh [3 g][8 ks][4 sub][64 col][8 e]   (49152 elems)
//                         gi [3 g][2 ks][4 sub][64 col][8 e]   (12288 elems)
//   k = ks*32 + sub*8 + e; col = block-local hcol; gi zero for k>=40
// then f32 bfused[768] = b_ih + W_ih@b_proj
#define WSQ 61440
#define WSBI (4 * WSQ)                    // 245760
#define PREP_N (245760 + 768 + B_N)

__global__ void prep(const float* __restrict__ Wp, const float* __restrict__ bp,
                     const float* __restrict__ Wih, const float* __restrict__ Whh,
                     const float* __restrict__ bih, const float* __restrict__ bhead,
                     __bf16* __restrict__ wsb, float* __restrict__ out) {
  int i = blockIdx.x * 256 + threadIdx.x;
  if (i < WSBI) {
    const int quarter = i / WSQ, r = i % WSQ;
    if (r < 49152) {  // gh
      const int g = r >> 14, ks = (r >> 11) & 7, sub = (r >> 9) & 3,
                col = (r >> 3) & 63, e = r & 7;
      const int gatecol = g * 256 + quarter * 64 + col;
      const int k = ks * 32 + sub * 8 + e;
      wsb[i] = (__bf16)Whh[(size_t)gatecol * 256 + k];
    } else {          // gi (fused)
      const int rr = r - 49152;
      const int g = rr >> 12, ks = (rr >> 11) & 1, sub = (rr >> 9) & 3,
                col = (rr >> 3) & 63, e = rr & 7;
      const int gatecol = g * 256 + quarter * 64 + col;
      const int k = ks * 32 + sub * 8 + e;
      float v = 0.f;
      if (k < IN_N)
        for (int p = 0; p < 128; ++p)
          v += Wih[(size_t)gatecol * 128 + p] * Wp[p * IN_N + k];
      wsb[i] = (__bf16)v;
    }
  } else if (i < WSBI + 768) {
    const int g = i - WSBI;
    float v = bih[g];
    for (int p = 0; p < 128; ++p) v += Wih[g * 128 + p] * bp[p];
    ((float*)(wsb + WSBI))[g] = v;
  } else if (i < PREP_N) {
    out[i - (WSBI + 768)] = bhead[0];  // pred init = bias; waves atomicAdd partials
  }
}

__device__ __forceinline__ void gload16(const __bf16* g, __bf16* l) {
  __builtin_amdgcn_global_load_lds(
      (const __attribute__((address_space(1))) void*)g,
      (__attribute__((address_space(3))) void*)l, 16, 0, 0);
}

__device__ __forceinline__ bf16x8 cvt8(float4 a, float4 b) {
  bf16x8 u;
  u[0] = (__bf16)a.x; u[1] = (__bf16)a.y; u[2] = (__bf16)a.z; u[3] = (__bf16)a.w;
  u[4] = (__bf16)b.x; u[5] = (__bf16)b.y; u[6] = (__bf16)b.z; u[7] = (__bf16)b.w;
  return u;
}

// 4096 blocks = 4 quarters x 1024 row-tiles; 1024 thr = 16 waves (4rw x 4cw).
// ONE 128-row x 64-hcol tile per block. LDS: gh weights 96KB + A-buffer 64KB.
// Phase 1: A-buffer holds giW(24KB)+x(16KB) -> gi MFMAs, h loads in flight.
// Phase 2: A-buffer holds h-tile -> gh MFMAs, epilogue. 3 barriers total.
// Wave = 32 rows x 16 cols (Mr=2): 1.2 MFMA per ds_read_b128 at 4 waves/SIMD.
__global__ __launch_bounds__(1024, 1) void gru_v16(
    const float* __restrict__ x, const float* __restrict__ h0,
    const __bf16* __restrict__ wsb, const float* __restrict__ bhh,
    const float* __restrict__ Whead, float* __restrict__ out) {
  __shared__ __bf16 WG[49152];   // 96 KB: gh [3][8][4][64][8]
  __shared__ __bf16 AH[32768];   // 64 KB: ph1 giW[0,12288)+xsw[12288,20480); ph2 h-tile
                                 // total 163840 B = 160 KiB exact

  const int tid = threadIdx.x;
  const int lane = tid & 63;
  const int w = tid >> 6;              // 0..15
  const int l15 = lane & 15;
  const int l4 = lane >> 4;
  const int rw = w >> 2, cw = w & 3;

  // XCD-chunked: 4 quarter-siblings of a row-tile adjacent -> h L2 reuse
  const int lin = (blockIdx.x & 7) * 512 + (blockIdx.x >> 3);
  const int quarter = lin & 3;
  const size_t row0 = (size_t)(lin >> 2) * 128;

  const int colB = cw * 16 + l15;      // block-local hcol 0..63
  const int hcol = quarter * 64 + colB;

  // ---- async weight staging: gh -> WG (96 chunks), giW -> AH[0..) (24 chunks) ----
  const __bf16* wsq = wsb + quarter * WSQ;
#pragma unroll
  for (int j = 0; j < 6; ++j) {
    const int idx = w * 6 + j;         // wave-uniform, 0..95
    gload16(wsq + idx * 512 + lane * 8, &WG[idx * 512]);
  }
#pragma unroll
  for (int j = 0; j < 2; ++j) {
    const int idx = j * 16 + w;        // wave-uniform
    if (idx < 24)
      gload16(wsq + 49152 + idx * 512 + lane * 8, &AH[idx * 512]);
  }

  // ---- h tile -> regs (cvt at arrival; 16 VGPR), hides under phase 1 ----
  bf16x8 hreg[4];
#pragma unroll
  for (int j = 0; j < 4; ++j) {
    const int c = tid + j * 1024;      // chunk 0..4095: row = c>>5, ci = c&31
    const float* s = h0 + (row0 + (c >> 5)) * H_N + (c & 31) * 8;
    hreg[j] = cvt8(*reinterpret_cast<const float4*>(s),
                   *reinterpret_cast<const float4*>(s + 4));
  }

  // ---- x tile -> AH[12288..): [128 row][8 chunk ^ (row&7)][8], pad 40->64 ----
  if (tid < 640) {
    const int row = tid / 5, kc = tid % 5;
    const float* s = x + (row0 + row) * IN_N + kc * 8;
    *reinterpret_cast<bf16x8*>(&AH[12288 + row * 64 + ((kc ^ (row & 7)) << 3)]) =
        cvt8(*reinterpret_cast<const float4*>(s),
             *reinterpret_cast<const float4*>(s + 4));
  } else {
    const int p = tid - 640;           // 0..383: zero pad chunks 5..7
    const int row = p / 3, kc = 5 + p % 3;
    bf16x8 z = {};
    *reinterpret_cast<bf16x8*>(&AH[12288 + row * 64 + ((kc ^ (row & 7)) << 3)]) = z;
  }

  const float* bfused = (const float*)(wsb + WSBI);
  const float bR = bfused[hcol] + bhh[hcol];
  const float bZ = bfused[256 + hcol] + bhh[256 + hcol];
  const float bI = bfused[512 + hcol];
  const float bH = bhh[512 + hcol];
  const float wh = Whead[hcol];

  __syncthreads();   // giW + x visible (vmcnt drained incl. WG)

  // ---- phase 1: gi (K=64 padded) ----
  f32x4 aR[2], aZ[2], aI[2], aH4[2];
#pragma unroll
  for (int mi = 0; mi < 2; ++mi) {
    aR[mi] = (f32x4){bR, bR, bR, bR};
    aZ[mi] = (f32x4){bZ, bZ, bZ, bZ};
    aI[mi] = (f32x4){bI, bI, bI, bI};
    aH4[mi] = (f32x4){bH, bH, bH, bH};
  }
  const int bofs = l4 * 512 + colB * 8;
#pragma unroll
  for (int ks = 0; ks < 2; ++ks) {
    const bf16x8 b0 = *reinterpret_cast<const bf16x8*>(&AH[(0 + ks) * 2048 + bofs]);
    const bf16x8 b1 = *reinterpret_cast<const bf16x8*>(&AH[(2 + ks) * 2048 + bofs]);
    const bf16x8 b2 = *reinterpret_cast<const bf16x8*>(&AH[(4 + ks) * 2048 + bofs]);
#pragma unroll
    for (int mi = 0; mi < 2; ++mi) {
      const int arow = rw * 32 + mi * 16 + l15;
      const bf16x8 a = *reinterpret_cast<const bf16x8*>(
          &AH[12288 + arow * 64 + (((ks * 4 + l4) ^ (arow & 7)) << 3)]);
      aR[mi] = MFMA(a, b0, aR[mi]);
      aZ[mi] = MFMA(a, b1, aZ[mi]);
      aI[mi] = MFMA(a, b2, aI[mi]);
    }
  }
  __syncthreads();   // gi reads of AH done

  // ---- write h tile: [128 row][32 chunk ^ (row&7)][8] ----
#pragma unroll
  for (int j = 0; j < 4; ++j) {
    const int c = tid + j * 1024;
    const int row = c >> 5, ci = c & 31;
    *reinterpret_cast<bf16x8*>(&AH[row * 256 + ((ci ^ (row & 7)) << 3)]) = hreg[j];
  }
  __syncthreads();

  // ---- phase 2: gh (K=256) ----
#pragma unroll
  for (int ks = 0; ks < 8; ++ks) {
    const bf16x8 b0 = *reinterpret_cast<const bf16x8*>(&WG[(0 + ks) * 2048 + bofs]);
    const bf16x8 b1 = *reinterpret_cast<const bf16x8*>(&WG[(8 + ks) * 2048 + bofs]);
    const bf16x8 b2 = *reinterpret_cast<const bf16x8*>(&WG[(16 + ks) * 2048 + bofs]);
#pragma unroll
    for (int mi = 0; mi < 2; ++mi) {
      const int arow = rw * 32 + mi * 16 + l15;
      const bf16x8 a = *reinterpret_cast<const bf16x8*>(
          &AH[arow * 256 + (((ks * 4 + l4) ^ (arow & 7)) << 3)]);
      aR[mi] = MFMA(a, b0, aR[mi]);
      aZ[mi] = MFMA(a, b1, aZ[mi]);
      aH4[mi] = MFMA(a, b2, aH4[mi]);
    }
  }

  // ---- epilogue: gates (f32), h_new store, pred partials; hv from h0 (L2-hot) ----
  float ps[2][4];
#pragma unroll
  for (int mi = 0; mi < 2; ++mi) {
#pragma unroll
    for (int r = 0; r < 4; ++r) {
      const int rowl = rw * 32 + mi * 16 + l4 * 4 + r;
      const float rg = 1.f / (1.f + __expf(-aR[mi][r]));
      const float zg = 1.f / (1.f + __expf(-aZ[mi][r]));
      const float e2 = __expf(2.f * (aI[mi][r] + rg * aH4[mi][r]));
      const float ng = (e2 - 1.f) / (e2 + 1.f);
      const float hv = h0[(row0 + rowl) * H_N + hcol];
      const float hn = (1.f - zg) * ng + zg * hv;
      out[(size_t)B_N + (row0 + rowl) * H_N + hcol] = hn;
      ps[mi][r] = hn * wh;
    }
  }
#pragma unroll
  for (int mi = 0; mi < 2; ++mi)
#pragma unroll
    for (int r = 0; r < 4; ++r) {
      float s = ps[mi][r];
      s += __shfl_xor(s, 1);
      s += __shfl_xor(s, 2);
      s += __shfl_xor(s, 4);
      s += __shfl_xor(s, 8);
      if (l15 == 0)
        atomicAdd(&out[row0 + rw * 32 + mi * 16 + l4 * 4 + r], s);
    }
}

extern "C" void kernel_launch(void* const* d_in, const int* in_sizes, int n_in,
                              void* d_out, int out_size, void* d_ws, size_t ws_size,
                              hipStream_t stream) {
  const float* x     = (const float*)d_in[0];
  const float* h0    = (const float*)d_in[1];
  const float* Wp    = (const float*)d_in[2];
  const float* bp    = (const float*)d_in[3];
  const float* Wih   = (const float*)d_in[4];
  const float* Whh   = (const float*)d_in[5];
  const float* bih   = (const float*)d_in[6];
  const float* bhh   = (const float*)d_in[7];
  const float* Whead = (const float*)d_in[8];
  const float* bhead = (const float*)d_in[9];
  float* out = (float*)d_out;
  __bf16* wsb = (__bf16*)d_ws;

  prep<<<(PREP_N + 255) / 256, 256, 0, stream>>>(Wp, bp, Wih, Whh, bih, bhead, wsb, out);
  gru_v16<<<4096, 1024, 0, stream>>>(x, h0, wsb, bhh, Whead, out);
}